// Round 1
// baseline (1483.895 us; speedup 1.0000x reference)
//
#include <hip/hip_runtime.h>
#include <cstdint>

// ============================================================================
// Supernetwork: conv-bn-relu-pool x3 backbone -> beam search -> expert dispatch
// All compute in fp32 (bf16 MFMA would flip beam-search top_k orderings).
// Intermediates NHWC. Conv bias omitted (cancelled exactly by BN mean-sub).
// Workspace requirement: ~135.2 MB.
// ============================================================================

// ---- ws layout (in floats) ----
static constexpr size_t O_STATS = 0;        // 192: [s1 sum32|s1 sq32|s2 sum|s2 sq|s3 sum|s3 sq]
static constexpr size_t O_W1T   = 256;      // 864   w1t[k*32+co], k=ci*9+kh*3+kw
static constexpr size_t O_W2T   = 1152;     // 9216  w2t[k*32+co], k=(kh*3+kw)*32+ci
static constexpr size_t O_W3T   = 10368;    // 9216
static constexpr size_t O_SCORES= 19584;    // 8192
static constexpr size_t O_P0    = 27776;    // 8192 each
static constexpr size_t O_P1    = 35968;
static constexpr size_t O_P2    = 44160;
static constexpr size_t O_OP0   = 52352;    // int32, 8192 each
static constexpr size_t O_OP1   = 60544;
static constexpr size_t O_OP2   = 68736;
static constexpr size_t O_SRC1  = 76928;    // int32
static constexpr size_t O_SRC2  = 85120;
static constexpr size_t O_H0    = 93312;    // 2048*128
static constexpr size_t O_H     = 355456;   // 8192*128
static constexpr size_t O_H2    = 1404032;  // 8192*128
static constexpr size_t O_HIDA  = 2452608;  // 8192*128
static constexpr size_t O_HIDB  = 3501184;  // 8192*128
static constexpr size_t O_S1P   = 4549760;  // 2048*225*32 NHWC
static constexpr size_t O_S2C   = 19295360; // 2048*169*32 NHWC
static constexpr size_t O_S2P   = 30371968; // 2048*36*32  NHWC
static constexpr size_t O_S3C   = 32731264; // 2048*16*32  NHWC
// total 33779840 floats = 135.1 MB

// ---------------------------------------------------------------------------
// K0: transpose conv weights to k-major [k][co] once per call
// ---------------------------------------------------------------------------
__global__ void prep_w(const float* __restrict__ w1, const float* __restrict__ w2,
                       const float* __restrict__ w3, float* __restrict__ w1t,
                       float* __restrict__ w2t, float* __restrict__ w3t) {
    int t = blockIdx.x * 256 + threadIdx.x;
    if (t < 864) {                       // w1 OIHW (32,3,3,3): k = ci*9+tap
        int co = t / 27, k = t % 27;
        w1t[k * 32 + co] = w1[t];
    }
    if (t < 9216) {                      // w2/w3 OIHW (32,32,3,3): k = tap*32+ci
        int co = t / 288, rest = t % 288;
        int ci = rest / 9, tap = rest % 9;
        int k = tap * 32 + ci;
        w2t[k * 32 + co] = w2[t];
        w3t[k * 32 + co] = w3[t];
    }
}

// ---------------------------------------------------------------------------
// conv1 helper: 4 pixels x 8 channels, K=27 (3ci x 3x3), img/wt in LDS
// ---------------------------------------------------------------------------
__device__ __forceinline__ void conv1_quad(const float* __restrict__ img,
                                           const float* __restrict__ wt,
                                           const int* __restrict__ base, int c0,
                                           float y[4][8]) {
#pragma unroll
    for (int k = 0; k < 27; ++k) {
        const int ci = k / 9, tap = k % 9;
        const int aoff = ci * 1024 + (tap / 3) * 32 + (tap % 3);
        float4 wa = *(const float4*)&wt[k * 32 + c0];
        float4 wb = *(const float4*)&wt[k * 32 + c0 + 4];
#pragma unroll
        for (int j = 0; j < 4; ++j) {
            float v = img[base[j] + aoff];
            y[j][0] += v * wa.x; y[j][1] += v * wa.y;
            y[j][2] += v * wa.z; y[j][3] += v * wa.w;
            y[j][4] += v * wb.x; y[j][5] += v * wb.y;
            y[j][6] += v * wb.z; y[j][7] += v * wb.w;
        }
    }
}

// ---------------------------------------------------------------------------
// K1: conv1 stats pass (no store). wave w = channels 8w..8w+7; lane = 4-px chunk
// ---------------------------------------------------------------------------
__global__ __launch_bounds__(256) void conv1_stats_kernel(
    const float* __restrict__ x, const float* __restrict__ w1t,
    float* __restrict__ stats) {
    __shared__ float img[3072];
    __shared__ float wt[864];
    const int n = blockIdx.x, t = threadIdx.x;
    const float* xin = x + (size_t)n * 3072;
    for (int i = t; i < 3072; i += 256) img[i] = xin[i];
    for (int i = t; i < 864; i += 256) wt[i] = w1t[i];
    __syncthreads();
    const int wv = t >> 6, lane = t & 63, c0 = wv * 8;
    float sm[8] = {}, sq[8] = {};
    for (int chunk = lane; chunk < 225; chunk += 64) {
        int base[4];
#pragma unroll
        for (int j = 0; j < 4; ++j) {
            int p = chunk * 4 + j;
            base[j] = (p / 30) * 32 + (p % 30);
        }
        float y[4][8] = {};
        conv1_quad(img, wt, base, c0, y);
#pragma unroll
        for (int j = 0; j < 4; ++j)
#pragma unroll
            for (int c = 0; c < 8; ++c) {
                float v = y[j][c];
                sm[c] += v; sq[c] += v * v;
            }
    }
#pragma unroll
    for (int off = 32; off > 0; off >>= 1)
#pragma unroll
        for (int c = 0; c < 8; ++c) {
            sm[c] += __shfl_down(sm[c], off);
            sq[c] += __shfl_down(sq[c], off);
        }
    if (lane == 0)
#pragma unroll
        for (int c = 0; c < 8; ++c) {
            atomicAdd(&stats[c0 + c], sm[c]);
            atomicAdd(&stats[32 + c0 + c], sq[c]);
        }
}

// ---------------------------------------------------------------------------
// K2: conv1 recompute + BN + relu + avgpool2 -> s1_pool NHWC (2048,15,15,32)
// ---------------------------------------------------------------------------
__global__ __launch_bounds__(256) void conv1_apply_kernel(
    const float* __restrict__ x, const float* __restrict__ w1t,
    const float* __restrict__ stats, const float* __restrict__ g,
    const float* __restrict__ be, float* __restrict__ s1p) {
    __shared__ float img[3072];
    __shared__ float wt[864];
    __shared__ float sc[32], sh[32];
    const int n = blockIdx.x, t = threadIdx.x;
    const float* xin = x + (size_t)n * 3072;
    for (int i = t; i < 3072; i += 256) img[i] = xin[i];
    for (int i = t; i < 864; i += 256) wt[i] = w1t[i];
    if (t < 32) {
        const float inv = 1.f / 1843200.f;  // 2048*900
        float mean = stats[t] * inv;
        float var = stats[32 + t] * inv - mean * mean;
        float s = g[t] * rsqrtf(var + 1e-5f);
        sc[t] = s; sh[t] = be[t] - mean * s;
    }
    __syncthreads();
    const int wv = t >> 6, lane = t & 63, c0 = wv * 8;
    for (int pp = lane; pp < 225; pp += 64) {
        const int ph = pp / 15, pw = pp % 15;
        int base[4];
#pragma unroll
        for (int j = 0; j < 4; ++j)
            base[j] = (2 * ph + (j >> 1)) * 32 + 2 * pw + (j & 1);
        float y[4][8] = {};
        conv1_quad(img, wt, base, c0, y);
        float ov[8];
#pragma unroll
        for (int c = 0; c < 8; ++c) {
            float s = sc[c0 + c], b = sh[c0 + c];
            float a0 = fmaxf(y[0][c] * s + b, 0.f);
            float a1 = fmaxf(y[1][c] * s + b, 0.f);
            float a2 = fmaxf(y[2][c] * s + b, 0.f);
            float a3 = fmaxf(y[3][c] * s + b, 0.f);
            ov[c] = 0.25f * (a0 + a1 + a2 + a3);
        }
        float* dst = s1p + ((size_t)n * 225 + pp) * 32 + c0;
        *(float4*)dst = make_float4(ov[0], ov[1], ov[2], ov[3]);
        *(float4*)(dst + 4) = make_float4(ov[4], ov[5], ov[6], ov[7]);
    }
}

// ---------------------------------------------------------------------------
// K3: conv2 NHWC (15,15,32)->(13,13,32). 1 img/block, thread = 4px x 8ch.
// Weights K-split into 2 phases to keep LDS under 64KB (47.2KB total).
// px 169..175 read in-bounds-of-LDS garbage; stores masked.
// ---------------------------------------------------------------------------
__global__ __launch_bounds__(192) void conv2_kernel(
    const float* __restrict__ s1p, const float* __restrict__ w2t,
    float* __restrict__ s2c) {
    __shared__ float img[7200];
    __shared__ float wt[4608];
    const int n = blockIdx.x, t = threadIdx.x;
    const float* src = s1p + (size_t)n * 7200;
    for (int i = t; i < 7200; i += 192) img[i] = src[i];
    const bool active = t < 176;
    const int chunk = t >> 2, cg = t & 3, c0 = cg * 8;
    int b32a[4], pv[4];
#pragma unroll
    for (int j = 0; j < 4; ++j) {
        int p = chunk * 4 + j;
        pv[j] = p;
        b32a[j] = ((p / 13) * 15 + (p % 13)) * 32;
    }
    float y[4][8] = {};
    for (int phse = 0; phse < 2; ++phse) {
        __syncthreads();
        for (int i = t; i < 4608; i += 192) wt[i] = w2t[phse * 4608 + i];
        __syncthreads();
        if (active) {
#pragma unroll 8
            for (int kk = 0; kk < 144; ++kk) {
                const int k = phse * 144 + kk;
                const int tap = k >> 5, ci = k & 31;
                const int aoff = ((tap / 3) * 15 + (tap % 3)) * 32 + ci;
                float4 wa = *(const float4*)&wt[kk * 32 + c0];
                float4 wb = *(const float4*)&wt[kk * 32 + c0 + 4];
#pragma unroll
                for (int j = 0; j < 4; ++j) {
                    float v = img[b32a[j] + aoff];
                    y[j][0] += v * wa.x; y[j][1] += v * wa.y;
                    y[j][2] += v * wa.z; y[j][3] += v * wa.w;
                    y[j][4] += v * wb.x; y[j][5] += v * wb.y;
                    y[j][6] += v * wb.z; y[j][7] += v * wb.w;
                }
            }
        }
    }
    if (active) {
#pragma unroll
        for (int j = 0; j < 4; ++j)
            if (pv[j] < 169) {
                float* dst = s2c + ((size_t)n * 169 + pv[j]) * 32 + c0;
                *(float4*)dst = make_float4(y[j][0], y[j][1], y[j][2], y[j][3]);
                *(float4*)(dst + 4) = make_float4(y[j][4], y[j][5], y[j][6], y[j][7]);
            }
    }
}

// ---------------------------------------------------------------------------
// K6: conv3 NHWC (6,6,32)->(4,4,32). 8 img/block, block 128, thread = 4px x 8ch
// ---------------------------------------------------------------------------
__global__ __launch_bounds__(128) void conv3_kernel(
    const float* __restrict__ s2p, const float* __restrict__ w3t,
    float* __restrict__ s3c) {
    __shared__ float img[9216];
    __shared__ float wt[4608];
    const int n0 = blockIdx.x * 8, t = threadIdx.x;
    const float* src = s2p + (size_t)n0 * 1152;
    for (int i = t; i < 9216; i += 128) img[i] = src[i];
    const int im = t >> 4, rem = t & 15, chunk = rem >> 2, cg = rem & 3, c0 = cg * 8;
    int b32a[4];
#pragma unroll
    for (int j = 0; j < 4; ++j) {
        int p = chunk * 4 + j;
        b32a[j] = im * 1152 + ((p / 4) * 6 + (p % 4)) * 32;
    }
    float y[4][8] = {};
    for (int phse = 0; phse < 2; ++phse) {
        __syncthreads();
        for (int i = t; i < 4608; i += 128) wt[i] = w3t[phse * 4608 + i];
        __syncthreads();
#pragma unroll 8
        for (int kk = 0; kk < 144; ++kk) {
            const int k = phse * 144 + kk;
            const int tap = k >> 5, ci = k & 31;
            const int aoff = ((tap / 3) * 6 + (tap % 3)) * 32 + ci;
            float4 wa = *(const float4*)&wt[kk * 32 + c0];
            float4 wb = *(const float4*)&wt[kk * 32 + c0 + 4];
#pragma unroll
            for (int j = 0; j < 4; ++j) {
                float v = img[b32a[j] + aoff];
                y[j][0] += v * wa.x; y[j][1] += v * wa.y;
                y[j][2] += v * wa.z; y[j][3] += v * wa.w;
                y[j][4] += v * wb.x; y[j][5] += v * wb.y;
                y[j][6] += v * wb.z; y[j][7] += v * wb.w;
            }
        }
    }
#pragma unroll
    for (int j = 0; j < 4; ++j) {
        float* dst = s3c + ((size_t)(n0 + im) * 16 + chunk * 4 + j) * 32 + c0;
        *(float4*)dst = make_float4(y[j][0], y[j][1], y[j][2], y[j][3]);
        *(float4*)(dst + 4) = make_float4(y[j][4], y[j][5], y[j][6], y[j][7]);
    }
}

// ---------------------------------------------------------------------------
// K4/K7: per-channel sum & sumsq over an NHWC buffer (C=32)
// ---------------------------------------------------------------------------
__global__ void stats_reduce(const float* __restrict__ buf, int total,
                             float* __restrict__ out) {
    __shared__ float rs[256], rq[256];
    const int t = threadIdx.x;
    float s = 0.f, q = 0.f;
    for (int i = blockIdx.x * 256 + t; i < total; i += gridDim.x * 256) {
        float v = buf[i];
        s += v; q += v * v;
    }
    rs[t] = s; rq[t] = q;
    __syncthreads();
    for (int off = 128; off >= 32; off >>= 1) {
        if (t < off) { rs[t] += rs[t + off]; rq[t] += rq[t + off]; }
        __syncthreads();
    }
    if (t < 32) {
        atomicAdd(&out[t], rs[t]);
        atomicAdd(&out[32 + t], rq[t]);
    }
}

// ---------------------------------------------------------------------------
// K5: BN+relu+avgpool2 for stage2: s2_conv (13,13) -> s2_pool (6,6) NHWC
// ---------------------------------------------------------------------------
__global__ void bn_pool2(const float* __restrict__ s2c, const float* __restrict__ stats,
                         const float* __restrict__ g, const float* __restrict__ be,
                         float* __restrict__ s2p) {
    __shared__ float sc[32], sh[32];
    const int t = threadIdx.x;
    if (t < 32) {
        const float inv = 1.f / 346112.f;  // 2048*169
        float mean = stats[t] * inv;
        float var = stats[32 + t] * inv - mean * mean;
        float s = g[t] * rsqrtf(var + 1e-5f);
        sc[t] = s; sh[t] = be[t] - mean * s;
    }
    __syncthreads();
    for (int idx = blockIdx.x * blockDim.x + t; idx < 2359296;
         idx += gridDim.x * blockDim.x) {
        const int ci = idx & 31, rest = idx >> 5;
        const int pp = rest % 36, n = rest / 36;
        const int ph = pp / 6, pw = pp % 6;
        const float* b = s2c + ((size_t)n * 169 + (2 * ph) * 13 + 2 * pw) * 32 + ci;
        const float s = sc[ci], h = sh[ci];
        float a0 = fmaxf(b[0] * s + h, 0.f);
        float a1 = fmaxf(b[32] * s + h, 0.f);
        float a2 = fmaxf(b[13 * 32] * s + h, 0.f);
        float a3 = fmaxf(b[14 * 32] * s + h, 0.f);
        s2p[idx] = 0.25f * (a0 + a1 + a2 + a3);
    }
}

// ---------------------------------------------------------------------------
// K8: BN+relu+avgpool2 for stage3 writing h0 in NCHW-flat order h0[n][c*4+h*2+w]
// ---------------------------------------------------------------------------
__global__ void bn_pool3_h0(const float* __restrict__ s3c, const float* __restrict__ stats,
                            const float* __restrict__ g, const float* __restrict__ be,
                            float* __restrict__ h0) {
    __shared__ float sc[32], sh[32];
    const int t = threadIdx.x;
    if (t < 32) {
        const float inv = 1.f / 32768.f;  // 2048*16
        float mean = stats[t] * inv;
        float var = stats[32 + t] * inv - mean * mean;
        float s = g[t] * rsqrtf(var + 1e-5f);
        sc[t] = s; sh[t] = be[t] - mean * s;
    }
    __syncthreads();
    const int idx = blockIdx.x * 256 + t;
    if (idx >= 262144) return;
    const int n = idx >> 7, rem = idx & 127;
    const int c = rem >> 2, q = rem & 3, ph = q >> 1, pw = q & 1;
    const float* b = s3c + ((size_t)n * 16 + 2 * ph * 4 + 2 * pw) * 32 + c;
    const float s = sc[c], h = sh[c];
    float a0 = fmaxf(b[0] * s + h, 0.f);
    float a1 = fmaxf(b[32] * s + h, 0.f);
    float a2 = fmaxf(b[128] * s + h, 0.f);
    float a3 = fmaxf(b[160] * s + h, 0.f);
    h0[idx] = 0.25f * (a0 + a1 + a2 + a3);
}

// ---------------------------------------------------------------------------
// K9: beam level 0: logits0 = h0.Who + bho; softmax/logsoftmax; stable sort-4
// one wave per sample
// ---------------------------------------------------------------------------
__global__ void beam0_kernel(const float* __restrict__ h0, const float* __restrict__ Who,
                             const float* __restrict__ bho, float* __restrict__ scores,
                             int* __restrict__ op0, float* __restrict__ p0) {
    const int n = blockIdx.x, lane = threadIdx.x;
    const float* hr = h0 + (size_t)n * 128;
    float pt[4] = {};
    for (int i = lane; i < 128; i += 64) {
        float hv = hr[i];
        pt[0] += hv * Who[i * 4 + 0];
        pt[1] += hv * Who[i * 4 + 1];
        pt[2] += hv * Who[i * 4 + 2];
        pt[3] += hv * Who[i * 4 + 3];
    }
#pragma unroll
    for (int off = 32; off > 0; off >>= 1)
#pragma unroll
        for (int o = 0; o < 4; ++o) pt[o] += __shfl_down(pt[o], off);
    if (lane == 0) {
        float lg[4], e[4], probs[4], logp[4];
#pragma unroll
        for (int o = 0; o < 4; ++o) lg[o] = pt[o] + bho[o];
        float m = fmaxf(fmaxf(lg[0], lg[1]), fmaxf(lg[2], lg[3]));
        float sum = 0.f;
#pragma unroll
        for (int o = 0; o < 4; ++o) { e[o] = expf(lg[o] - m); sum += e[o]; }
        float lse = logf(sum);
#pragma unroll
        for (int o = 0; o < 4; ++o) {
            probs[o] = e[o] / sum;
            logp[o] = lg[o] - m - lse;
        }
        bool used[4] = {false, false, false, false};
        for (int slot = 0; slot < 4; ++slot) {
            int best = 0; float bv = -INFINITY;
            for (int o = 0; o < 4; ++o)
                if (!used[o] && logp[o] > bv) { bv = logp[o]; best = o; }
            used[best] = true;
            scores[n * 4 + slot] = bv;
            op0[n * 4 + slot] = best;
            p0[n * 4 + slot] = probs[best];
        }
    }
}

// ---------------------------------------------------------------------------
// K11/K13: beam level >=1: 16 cand = scores[b]+logp[b][o]; stable top-4
// one wave per sample
// ---------------------------------------------------------------------------
__global__ void beam_level(const float* __restrict__ h, const float* __restrict__ Who,
                           const float* __restrict__ bho, float* __restrict__ scores,
                           int* __restrict__ opL, float* __restrict__ pL,
                           int* __restrict__ srcL) {
    __shared__ float logits[16], cand[16], pr[16];
    const int n = blockIdx.x, l = threadIdx.x;
    const int b = l >> 4, o = (l >> 2) & 3, qt = l & 3;
    const float* hr = h + ((size_t)n * 4 + b) * 128;
    float s = 0.f;
    for (int k = qt * 32; k < qt * 32 + 32; ++k) s += hr[k] * Who[k * 4 + o];
    s += __shfl_xor(s, 1);
    s += __shfl_xor(s, 2);
    if (qt == 0) logits[b * 4 + o] = s + bho[o];
    __syncthreads();
    if (l < 4) {
        float lg[4];
#pragma unroll
        for (int o2 = 0; o2 < 4; ++o2) lg[o2] = logits[l * 4 + o2];
        float m = fmaxf(fmaxf(lg[0], lg[1]), fmaxf(lg[2], lg[3]));
        float e[4], sum = 0.f;
#pragma unroll
        for (int o2 = 0; o2 < 4; ++o2) { e[o2] = expf(lg[o2] - m); sum += e[o2]; }
        float lse = logf(sum);
        float sb = scores[n * 4 + l];
#pragma unroll
        for (int o2 = 0; o2 < 4; ++o2) {
            pr[l * 4 + o2] = e[o2] / sum;
            cand[l * 4 + o2] = sb + (lg[o2] - m - lse);
        }
    }
    __syncthreads();
    if (l == 0) {
        bool used[16];
#pragma unroll
        for (int f = 0; f < 16; ++f) used[f] = false;
        float ns[4], np[4]; int nop[4], nsrc[4];
        for (int slot = 0; slot < 4; ++slot) {
            int best = 0; float bv = -INFINITY;
            for (int f = 0; f < 16; ++f)
                if (!used[f] && cand[f] > bv) { bv = cand[f]; best = f; }
            used[best] = true;
            ns[slot] = bv; nsrc[slot] = best >> 2; nop[slot] = best & 3;
            np[slot] = pr[best];
        }
        for (int slot = 0; slot < 4; ++slot) {
            scores[n * 4 + slot] = ns[slot];
            opL[n * 4 + slot] = nop[slot];
            pL[n * 4 + slot] = np[slot];
            srcL[n * 4 + slot] = nsrc[slot];
        }
    }
}

// ---------------------------------------------------------------------------
// K10/K12: h = tanh(src_row @ W_hh + E_op[op] + b_h). 2 rows x 128 cols/block.
// mode 0: src row = h0[r>>2];  mode 1: src row = in[(r&~3)+srcL[r]]
// ---------------------------------------------------------------------------
__global__ __launch_bounds__(256) void h_update(
    const float* __restrict__ in, int mode, const int* __restrict__ srcL,
    const int* __restrict__ opL, const float* __restrict__ Whh,
    const float* __restrict__ Eop, const float* __restrict__ bh,
    float* __restrict__ out) {
    __shared__ float A[256];
    const int r0 = blockIdx.x * 2, t = threadIdx.x;
    const int row = t >> 7, j = t & 127;
    const int r = r0 + row;
    const float* src;
    if (mode == 0) src = in + (size_t)(r >> 2) * 128;
    else           src = in + (size_t)((r & ~3) + srcL[r]) * 128;
    A[t] = src[j];
    __syncthreads();
    float acc = 0.f;
#pragma unroll 8
    for (int k = 0; k < 128; ++k) acc += A[row * 128 + k] * Whh[k * 128 + j];
    out[(size_t)r * 128 + j] = tanhf(acc + Eop[opL[r] * 128 + j] + bh[j]);
}

// ---------------------------------------------------------------------------
// K14-16: dispatch: per row apply only the SELECTED expert (op<3) or identity.
// out = relu((hid @ exp_w[op] + exp_b[op]) * p)  |  relu(hid * p)
// 2 rows x 128 cols per block; each row spans 2 full waves (no divergence).
// ---------------------------------------------------------------------------
__global__ __launch_bounds__(256) void dispatch_kernel(
    const float* __restrict__ in, int mode, const int* __restrict__ opL,
    const float* __restrict__ pL, const float* __restrict__ expw,
    const float* __restrict__ expb, float* __restrict__ out) {
    __shared__ float A[256];
    const int r0 = blockIdx.x * 2, t = threadIdx.x;
    const int row = t >> 7, j = t & 127;
    const int r = r0 + row;
    const float* src = (mode == 0) ? in + (size_t)(r >> 2) * 128
                                   : in + (size_t)r * 128;
    A[t] = src[j];
    __syncthreads();
    const int op = opL[r];
    const float p = pL[r];
    float res;
    if (op < 3) {
        const float* Bw = expw + (size_t)op * 16384;
        float acc = 0.f;
#pragma unroll 8
        for (int k = 0; k < 128; ++k) acc += A[row * 128 + k] * Bw[k * 128 + j];
        res = (acc + expb[op * 128 + j]) * p;
    } else {
        res = A[row * 128 + j] * p;
    }
    out[(size_t)r * 128 + j] = fmaxf(res, 0.f);
}

// ---------------------------------------------------------------------------
// K17: final head: out = hid @ out_w + out_b  (8192 x 10)
// ---------------------------------------------------------------------------
__global__ void final_kernel(const float* __restrict__ hid, const float* __restrict__ ow,
                             const float* __restrict__ ob, float* __restrict__ out) {
    const int idx = blockIdx.x * 256 + threadIdx.x;
    if (idx >= 81920) return;
    const int r = idx / 10, o = idx % 10;
    const float* hr = hid + (size_t)r * 128;
    float acc = ob[o];
#pragma unroll 8
    for (int k = 0; k < 128; ++k) acc += hr[k] * ow[k * 10 + o];
    out[idx] = acc;
}

// ===========================================================================
extern "C" void kernel_launch(void* const* d_in, const int* in_sizes, int n_in,
                              void* d_out, int out_size, void* d_ws, size_t ws_size,
                              hipStream_t stream) {
    const float* x    = (const float*)d_in[0];
    const float* cw1  = (const float*)d_in[1];
    const float* g1   = (const float*)d_in[3];
    const float* be1  = (const float*)d_in[4];
    const float* cw2  = (const float*)d_in[5];
    const float* g2   = (const float*)d_in[7];
    const float* be2  = (const float*)d_in[8];
    const float* cw3  = (const float*)d_in[9];
    const float* g3   = (const float*)d_in[11];
    const float* be3  = (const float*)d_in[12];
    const float* Whh  = (const float*)d_in[13];
    const float* bh   = (const float*)d_in[14];
    const float* Eop  = (const float*)d_in[15];
    const float* Who  = (const float*)d_in[16];
    const float* bho  = (const float*)d_in[17];
    const float* expw = (const float*)d_in[18];
    const float* expb = (const float*)d_in[19];
    const float* outw = (const float*)d_in[20];
    const float* outb = (const float*)d_in[21];
    float* ws  = (float*)d_ws;
    float* out = (float*)d_out;

    // zero the BN stats accumulators (ws is poisoned 0xAA each launch)
    hipMemsetAsync(ws + O_STATS, 0, 768, stream);

    prep_w<<<36, 256, 0, stream>>>(cw1, cw2, cw3, ws + O_W1T, ws + O_W2T, ws + O_W3T);

    // ---- backbone ----
    conv1_stats_kernel<<<2048, 256, 0, stream>>>(x, ws + O_W1T, ws + O_STATS);
    conv1_apply_kernel<<<2048, 256, 0, stream>>>(x, ws + O_W1T, ws + O_STATS,
                                                 g1, be1, ws + O_S1P);
    conv2_kernel<<<2048, 192, 0, stream>>>(ws + O_S1P, ws + O_W2T, ws + O_S2C);
    stats_reduce<<<1024, 256, 0, stream>>>(ws + O_S2C, 2048 * 169 * 32,
                                           ws + O_STATS + 64);
    bn_pool2<<<2048, 256, 0, stream>>>(ws + O_S2C, ws + O_STATS + 64, g2, be2,
                                       ws + O_S2P);
    conv3_kernel<<<256, 128, 0, stream>>>(ws + O_S2P, ws + O_W3T, ws + O_S3C);
    stats_reduce<<<256, 256, 0, stream>>>(ws + O_S3C, 2048 * 16 * 32,
                                          ws + O_STATS + 128);
    bn_pool3_h0<<<1024, 256, 0, stream>>>(ws + O_S3C, ws + O_STATS + 128, g3, be3,
                                          ws + O_H0);

    // ---- beam search ----
    beam0_kernel<<<2048, 64, 0, stream>>>(ws + O_H0, Who, bho, ws + O_SCORES,
                                          (int*)(ws + O_OP0), ws + O_P0);
    h_update<<<4096, 256, 0, stream>>>(ws + O_H0, 0, (int*)(ws + O_SRC2),
                                       (int*)(ws + O_OP0), Whh, Eop, bh, ws + O_H);
    beam_level<<<2048, 64, 0, stream>>>(ws + O_H, Who, bho, ws + O_SCORES,
                                        (int*)(ws + O_OP1), ws + O_P1,
                                        (int*)(ws + O_SRC1));
    h_update<<<4096, 256, 0, stream>>>(ws + O_H, 1, (int*)(ws + O_SRC1),
                                       (int*)(ws + O_OP1), Whh, Eop, bh, ws + O_H2);
    beam_level<<<2048, 64, 0, stream>>>(ws + O_H2, Who, bho, ws + O_SCORES,
                                        (int*)(ws + O_OP2), ws + O_P2,
                                        (int*)(ws + O_SRC2));

    // ---- expert dispatch (3 rounds) + head ----
    dispatch_kernel<<<4096, 256, 0, stream>>>(ws + O_H0, 0, (int*)(ws + O_OP0),
                                              ws + O_P0, expw, expb, ws + O_HIDA);
    dispatch_kernel<<<4096, 256, 0, stream>>>(ws + O_HIDA, 1, (int*)(ws + O_OP1),
                                              ws + O_P1, expw, expb, ws + O_HIDB);
    dispatch_kernel<<<4096, 256, 0, stream>>>(ws + O_HIDB, 1, (int*)(ws + O_OP2),
                                              ws + O_P2, expw, expb, ws + O_HIDA);
    final_kernel<<<320, 256, 0, stream>>>(ws + O_HIDA, outw, outb, out);
}

// Round 2
// 868.125 us; speedup vs baseline: 1.7093x; 1.7093x over previous
//
#include <hip/hip_runtime.h>
#include <cstdint>

// ============================================================================
// Supernetwork: conv-bn-relu-pool x3 backbone -> beam search -> expert dispatch
// All compute in fp32 (bf16 MFMA would flip beam-search top_k orderings).
// Intermediates NHWC. Conv bias omitted (cancelled exactly by BN mean-sub).
// R1 changes: (a) stats via per-block partials + finalize kernel (no atomics,
// deterministic); (b) LDS pixel stride padded to 33 in all convs (was 32 ->
// bank = ci for all lanes = 16-way conflict).
// ============================================================================

// ---- ws layout (in floats) ----
static constexpr size_t O_SC    = 0;        // 192: [sc1|sh1|sc2|sh2|sc3|sh3] (64 each stage)
static constexpr size_t O_W1T   = 256;      // 864   w1t[k*32+co], k=ci*9+kh*3+kw
static constexpr size_t O_W2T   = 1152;     // 9216  w2t[k*32+co], k=(kh*3+kw)*32+ci
static constexpr size_t O_W3T   = 10368;    // 9216
static constexpr size_t O_SCORES= 19584;    // 8192
static constexpr size_t O_P0    = 27776;    // 8192 each
static constexpr size_t O_P1    = 35968;
static constexpr size_t O_P2    = 44160;
static constexpr size_t O_OP0   = 52352;    // int32, 8192 each
static constexpr size_t O_OP1   = 60544;
static constexpr size_t O_OP2   = 68736;
static constexpr size_t O_SRC1  = 76928;    // int32
static constexpr size_t O_SRC2  = 85120;
static constexpr size_t O_H0    = 93312;    // 2048*128
static constexpr size_t O_H     = 355456;   // 8192*128 (beam h; reused as stats partials in backbone)
static constexpr size_t O_H2    = 1404032;  // 8192*128
static constexpr size_t O_HIDA  = 2452608;  // 8192*128
static constexpr size_t O_HIDB  = 3501184;  // 8192*128
static constexpr size_t O_S1P   = 4549760;  // 2048*225*32 NHWC
static constexpr size_t O_S2C   = 19295360; // 2048*169*32 NHWC
static constexpr size_t O_S2P   = 30371968; // 2048*36*32  NHWC
static constexpr size_t O_S3C   = 32731264; // 2048*16*32  NHWC
static constexpr size_t O_PART  = O_H;      // per-block stats partials (max 2048*64)
// total 33779840 floats = 135.1 MB

// ---------------------------------------------------------------------------
// K0: transpose conv weights to k-major [k][co] once per call
// ---------------------------------------------------------------------------
__global__ void prep_w(const float* __restrict__ w1, const float* __restrict__ w2,
                       const float* __restrict__ w3, float* __restrict__ w1t,
                       float* __restrict__ w2t, float* __restrict__ w3t) {
    int t = blockIdx.x * 256 + threadIdx.x;
    if (t < 864) {                       // w1 OIHW (32,3,3,3): k = ci*9+tap
        int co = t / 27, k = t % 27;
        w1t[k * 32 + co] = w1[t];
    }
    if (t < 9216) {                      // w2/w3 OIHW (32,32,3,3): k = tap*32+ci
        int co = t / 288, rest = t % 288;
        int ci = rest / 9, tap = rest % 9;
        int k = tap * 32 + ci;
        w2t[k * 32 + co] = w2[t];
        w3t[k * 32 + co] = w3[t];
    }
}

// ---------------------------------------------------------------------------
// finalize_stats: reduce per-block partials [nblocks][64] (sum32|sq32) and
// write sc/sh (64 floats). 1 block, 256 threads.
// ---------------------------------------------------------------------------
__global__ __launch_bounds__(256) void finalize_stats(
    const float* __restrict__ part, int nblocks, float invcount,
    const float* __restrict__ g, const float* __restrict__ be,
    float* __restrict__ scsh) {
    __shared__ float red[256];
    const int t = threadIdx.x;
    const int c = t & 63, grp = t >> 6;
    float s = 0.f;
    for (int i = grp; i < nblocks; i += 4) s += part[(size_t)i * 64 + c];
    red[t] = s;
    __syncthreads();
    if (t < 64) red[t] = red[t] + red[64 + t] + red[128 + t] + red[192 + t];
    __syncthreads();
    if (t < 32) {
        float mean = red[t] * invcount;
        float var = red[32 + t] * invcount - mean * mean;
        float sc = g[t] * rsqrtf(var + 1e-5f);
        scsh[t] = sc;
        scsh[32 + t] = be[t] - mean * sc;
    }
}

// ---------------------------------------------------------------------------
// conv1 helper: 4 pixels x 8 channels, K=27 (3ci x 3x3), img/wt in LDS
// img layout: [ci][row][33] (row padded 32->33 to break bank aliasing)
// ---------------------------------------------------------------------------
__device__ __forceinline__ void conv1_quad(const float* __restrict__ img,
                                           const float* __restrict__ wt,
                                           const int* __restrict__ base, int c0,
                                           float y[4][8]) {
#pragma unroll
    for (int k = 0; k < 27; ++k) {
        const int ci = k / 9, tap = k % 9;
        const int aoff = ci * 1056 + (tap / 3) * 33 + (tap % 3);
        float4 wa = *(const float4*)&wt[k * 32 + c0];
        float4 wb = *(const float4*)&wt[k * 32 + c0 + 4];
#pragma unroll
        for (int j = 0; j < 4; ++j) {
            float v = img[base[j] + aoff];
            y[j][0] += v * wa.x; y[j][1] += v * wa.y;
            y[j][2] += v * wa.z; y[j][3] += v * wa.w;
            y[j][4] += v * wb.x; y[j][5] += v * wb.y;
            y[j][6] += v * wb.z; y[j][7] += v * wb.w;
        }
    }
}

// ---------------------------------------------------------------------------
// K1: conv1 stats pass. wave wv = channels 8wv..; writes per-block partials.
// ---------------------------------------------------------------------------
__global__ __launch_bounds__(256) void conv1_stats_kernel(
    const float* __restrict__ x, const float* __restrict__ w1t,
    float* __restrict__ part) {
    __shared__ float img[3168];   // 3*32*33
    __shared__ float wt[864];
    const int n = blockIdx.x, t = threadIdx.x;
    const float* xin = x + (size_t)n * 3072;
    for (int i = t; i < 3072; i += 256) {
        int ci = i >> 10, rem = i & 1023;
        img[ci * 1056 + (rem >> 5) * 33 + (rem & 31)] = xin[i];
    }
    for (int i = t; i < 864; i += 256) wt[i] = w1t[i];
    __syncthreads();
    const int wv = t >> 6, lane = t & 63, c0 = wv * 8;
    float sm[8] = {}, sq[8] = {};
    for (int chunk = lane; chunk < 225; chunk += 64) {
        int base[4];
#pragma unroll
        for (int j = 0; j < 4; ++j) {
            int p = chunk * 4 + j;
            base[j] = (p / 30) * 33 + (p % 30);
        }
        float y[4][8] = {};
        conv1_quad(img, wt, base, c0, y);
#pragma unroll
        for (int j = 0; j < 4; ++j)
#pragma unroll
            for (int c = 0; c < 8; ++c) {
                float v = y[j][c];
                sm[c] += v; sq[c] += v * v;
            }
    }
#pragma unroll
    for (int off = 32; off > 0; off >>= 1)
#pragma unroll
        for (int c = 0; c < 8; ++c) {
            sm[c] += __shfl_down(sm[c], off);
            sq[c] += __shfl_down(sq[c], off);
        }
    if (lane == 0) {
        float* dst = part + (size_t)n * 64;
#pragma unroll
        for (int c = 0; c < 8; ++c) {
            dst[c0 + c] = sm[c];
            dst[32 + c0 + c] = sq[c];
        }
    }
}

// ---------------------------------------------------------------------------
// K2: conv1 recompute + BN + relu + avgpool2 -> s1_pool NHWC (2048,15,15,32)
// ---------------------------------------------------------------------------
__global__ __launch_bounds__(256) void conv1_apply_kernel(
    const float* __restrict__ x, const float* __restrict__ w1t,
    const float* __restrict__ scsh, float* __restrict__ s1p) {
    __shared__ float img[3168];
    __shared__ float wt[864];
    __shared__ float bn[64];
    const int n = blockIdx.x, t = threadIdx.x;
    const float* xin = x + (size_t)n * 3072;
    for (int i = t; i < 3072; i += 256) {
        int ci = i >> 10, rem = i & 1023;
        img[ci * 1056 + (rem >> 5) * 33 + (rem & 31)] = xin[i];
    }
    for (int i = t; i < 864; i += 256) wt[i] = w1t[i];
    if (t < 64) bn[t] = scsh[t];
    __syncthreads();
    const int wv = t >> 6, lane = t & 63, c0 = wv * 8;
    for (int pp = lane; pp < 225; pp += 64) {
        const int ph = pp / 15, pw = pp % 15;
        int base[4];
#pragma unroll
        for (int j = 0; j < 4; ++j)
            base[j] = (2 * ph + (j >> 1)) * 33 + 2 * pw + (j & 1);
        float y[4][8] = {};
        conv1_quad(img, wt, base, c0, y);
        float ov[8];
#pragma unroll
        for (int c = 0; c < 8; ++c) {
            float s = bn[c0 + c], b = bn[32 + c0 + c];
            float a0 = fmaxf(y[0][c] * s + b, 0.f);
            float a1 = fmaxf(y[1][c] * s + b, 0.f);
            float a2 = fmaxf(y[2][c] * s + b, 0.f);
            float a3 = fmaxf(y[3][c] * s + b, 0.f);
            ov[c] = 0.25f * (a0 + a1 + a2 + a3);
        }
        float* dst = s1p + ((size_t)n * 225 + pp) * 32 + c0;
        *(float4*)dst = make_float4(ov[0], ov[1], ov[2], ov[3]);
        *(float4*)(dst + 4) = make_float4(ov[4], ov[5], ov[6], ov[7]);
    }
}

// ---------------------------------------------------------------------------
// K3: conv2 NHWC (15,15,32)->(13,13,32). 1 img/block, thread = 4px x 8ch.
// LDS img pixel stride padded to 33. Weights K-split into 2 phases.
// px 169..175 read in-bounds-of-LDS garbage; stores masked.
// ---------------------------------------------------------------------------
__global__ __launch_bounds__(192) void conv2_kernel(
    const float* __restrict__ s1p, const float* __restrict__ w2t,
    float* __restrict__ s2c) {
    __shared__ float img[7425];  // 225*33
    __shared__ float wt[4608];
    const int n = blockIdx.x, t = threadIdx.x;
    const float* src = s1p + (size_t)n * 7200;
    for (int i = t; i < 7200; i += 192) img[(i >> 5) * 33 + (i & 31)] = src[i];
    const bool active = t < 176;
    const int chunk = t >> 2, cg = t & 3, c0 = cg * 8;
    int b32a[4], pv[4];
#pragma unroll
    for (int j = 0; j < 4; ++j) {
        int p = chunk * 4 + j;
        pv[j] = p;
        b32a[j] = ((p / 13) * 15 + (p % 13)) * 33;
    }
    float y[4][8] = {};
    for (int phse = 0; phse < 2; ++phse) {
        __syncthreads();
        for (int i = t; i < 4608; i += 192) wt[i] = w2t[phse * 4608 + i];
        __syncthreads();
        if (active) {
#pragma unroll 8
            for (int kk = 0; kk < 144; ++kk) {
                const int k = phse * 144 + kk;
                const int tap = k >> 5, ci = k & 31;
                const int aoff = ((tap / 3) * 15 + (tap % 3)) * 33 + ci;
                float4 wa = *(const float4*)&wt[kk * 32 + c0];
                float4 wb = *(const float4*)&wt[kk * 32 + c0 + 4];
#pragma unroll
                for (int j = 0; j < 4; ++j) {
                    float v = img[b32a[j] + aoff];
                    y[j][0] += v * wa.x; y[j][1] += v * wa.y;
                    y[j][2] += v * wa.z; y[j][3] += v * wa.w;
                    y[j][4] += v * wb.x; y[j][5] += v * wb.y;
                    y[j][6] += v * wb.z; y[j][7] += v * wb.w;
                }
            }
        }
    }
    if (active) {
#pragma unroll
        for (int j = 0; j < 4; ++j)
            if (pv[j] < 169) {
                float* dst = s2c + ((size_t)n * 169 + pv[j]) * 32 + c0;
                *(float4*)dst = make_float4(y[j][0], y[j][1], y[j][2], y[j][3]);
                *(float4*)(dst + 4) = make_float4(y[j][4], y[j][5], y[j][6], y[j][7]);
            }
    }
}

// ---------------------------------------------------------------------------
// K6: conv3 NHWC (6,6,32)->(4,4,32). 8 img/block, block 128, thread = 4px x 8ch
// LDS: pixel stride 33, image stride 1188.
// ---------------------------------------------------------------------------
__global__ __launch_bounds__(128) void conv3_kernel(
    const float* __restrict__ s2p, const float* __restrict__ w3t,
    float* __restrict__ s3c) {
    __shared__ float img[9504];  // 8*36*33
    __shared__ float wt[4608];
    const int n0 = blockIdx.x * 8, t = threadIdx.x;
    const float* src = s2p + (size_t)n0 * 1152;
    for (int i = t; i < 9216; i += 128) {
        int im = i / 1152, rem = i % 1152;
        img[im * 1188 + (rem >> 5) * 33 + (rem & 31)] = src[i];
    }
    const int im = t >> 4, rem = t & 15, chunk = rem >> 2, cg = rem & 3, c0 = cg * 8;
    int b32a[4];
#pragma unroll
    for (int j = 0; j < 4; ++j) {
        int p = chunk * 4 + j;
        b32a[j] = im * 1188 + ((p / 4) * 6 + (p % 4)) * 33;
    }
    float y[4][8] = {};
    for (int phse = 0; phse < 2; ++phse) {
        __syncthreads();
        for (int i = t; i < 4608; i += 128) wt[i] = w3t[phse * 4608 + i];
        __syncthreads();
#pragma unroll 8
        for (int kk = 0; kk < 144; ++kk) {
            const int k = phse * 144 + kk;
            const int tap = k >> 5, ci = k & 31;
            const int aoff = ((tap / 3) * 6 + (tap % 3)) * 33 + ci;
            float4 wa = *(const float4*)&wt[kk * 32 + c0];
            float4 wb = *(const float4*)&wt[kk * 32 + c0 + 4];
#pragma unroll
            for (int j = 0; j < 4; ++j) {
                float v = img[b32a[j] + aoff];
                y[j][0] += v * wa.x; y[j][1] += v * wa.y;
                y[j][2] += v * wa.z; y[j][3] += v * wa.w;
                y[j][4] += v * wb.x; y[j][5] += v * wb.y;
                y[j][6] += v * wb.z; y[j][7] += v * wb.w;
            }
        }
    }
#pragma unroll
    for (int j = 0; j < 4; ++j) {
        float* dst = s3c + ((size_t)(n0 + im) * 16 + chunk * 4 + j) * 32 + c0;
        *(float4*)dst = make_float4(y[j][0], y[j][1], y[j][2], y[j][3]);
        *(float4*)(dst + 4) = make_float4(y[j][4], y[j][5], y[j][6], y[j][7]);
    }
}

// ---------------------------------------------------------------------------
// K4/K7: per-channel sum & sumsq over NHWC buffer (C=32) -> per-block partials
// ---------------------------------------------------------------------------
__global__ void stats_partial(const float* __restrict__ buf, int total,
                              float* __restrict__ part) {
    __shared__ float rs[256], rq[256];
    const int t = threadIdx.x;
    float s = 0.f, q = 0.f;
    for (int i = blockIdx.x * 256 + t; i < total; i += gridDim.x * 256) {
        float v = buf[i];
        s += v; q += v * v;
    }
    rs[t] = s; rq[t] = q;
    __syncthreads();
    for (int off = 128; off >= 32; off >>= 1) {
        if (t < off) { rs[t] += rs[t + off]; rq[t] += rq[t + off]; }
        __syncthreads();
    }
    if (t < 32) {
        part[(size_t)blockIdx.x * 64 + t] = rs[t];
        part[(size_t)blockIdx.x * 64 + 32 + t] = rq[t];
    }
}

// ---------------------------------------------------------------------------
// K5: BN+relu+avgpool2 for stage2: s2_conv (13,13) -> s2_pool (6,6) NHWC
// ---------------------------------------------------------------------------
__global__ void bn_pool2(const float* __restrict__ s2c, const float* __restrict__ scsh,
                         float* __restrict__ s2p) {
    __shared__ float bn[64];
    const int t = threadIdx.x;
    if (t < 64) bn[t] = scsh[t];
    __syncthreads();
    for (int idx = blockIdx.x * blockDim.x + t; idx < 2359296;
         idx += gridDim.x * blockDim.x) {
        const int ci = idx & 31, rest = idx >> 5;
        const int pp = rest % 36, n = rest / 36;
        const int ph = pp / 6, pw = pp % 6;
        const float* b = s2c + ((size_t)n * 169 + (2 * ph) * 13 + 2 * pw) * 32 + ci;
        const float s = bn[ci], h = bn[32 + ci];
        float a0 = fmaxf(b[0] * s + h, 0.f);
        float a1 = fmaxf(b[32] * s + h, 0.f);
        float a2 = fmaxf(b[13 * 32] * s + h, 0.f);
        float a3 = fmaxf(b[14 * 32] * s + h, 0.f);
        s2p[idx] = 0.25f * (a0 + a1 + a2 + a3);
    }
}

// ---------------------------------------------------------------------------
// K8: BN+relu+avgpool2 for stage3 writing h0 in NCHW-flat order h0[n][c*4+h*2+w]
// ---------------------------------------------------------------------------
__global__ void bn_pool3_h0(const float* __restrict__ s3c, const float* __restrict__ scsh,
                            float* __restrict__ h0) {
    __shared__ float bn[64];
    const int t = threadIdx.x;
    if (t < 64) bn[t] = scsh[t];
    __syncthreads();
    const int idx = blockIdx.x * 256 + t;
    if (idx >= 262144) return;
    const int n = idx >> 7, rem = idx & 127;
    const int c = rem >> 2, q = rem & 3, ph = q >> 1, pw = q & 1;
    const float* b = s3c + ((size_t)n * 16 + 2 * ph * 4 + 2 * pw) * 32 + c;
    const float s = bn[c], h = bn[32 + c];
    float a0 = fmaxf(b[0] * s + h, 0.f);
    float a1 = fmaxf(b[32] * s + h, 0.f);
    float a2 = fmaxf(b[128] * s + h, 0.f);
    float a3 = fmaxf(b[160] * s + h, 0.f);
    h0[idx] = 0.25f * (a0 + a1 + a2 + a3);
}

// ---------------------------------------------------------------------------
// K9: beam level 0: logits0 = h0.Who + bho; softmax/logsoftmax; stable sort-4
// one wave per sample
// ---------------------------------------------------------------------------
__global__ void beam0_kernel(const float* __restrict__ h0, const float* __restrict__ Who,
                             const float* __restrict__ bho, float* __restrict__ scores,
                             int* __restrict__ op0, float* __restrict__ p0) {
    const int n = blockIdx.x, lane = threadIdx.x;
    const float* hr = h0 + (size_t)n * 128;
    float pt[4] = {};
    for (int i = lane; i < 128; i += 64) {
        float hv = hr[i];
        pt[0] += hv * Who[i * 4 + 0];
        pt[1] += hv * Who[i * 4 + 1];
        pt[2] += hv * Who[i * 4 + 2];
        pt[3] += hv * Who[i * 4 + 3];
    }
#pragma unroll
    for (int off = 32; off > 0; off >>= 1)
#pragma unroll
        for (int o = 0; o < 4; ++o) pt[o] += __shfl_down(pt[o], off);
    if (lane == 0) {
        float lg[4], e[4], probs[4], logp[4];
#pragma unroll
        for (int o = 0; o < 4; ++o) lg[o] = pt[o] + bho[o];
        float m = fmaxf(fmaxf(lg[0], lg[1]), fmaxf(lg[2], lg[3]));
        float sum = 0.f;
#pragma unroll
        for (int o = 0; o < 4; ++o) { e[o] = expf(lg[o] - m); sum += e[o]; }
        float lse = logf(sum);
#pragma unroll
        for (int o = 0; o < 4; ++o) {
            probs[o] = e[o] / sum;
            logp[o] = lg[o] - m - lse;
        }
        bool used[4] = {false, false, false, false};
        for (int slot = 0; slot < 4; ++slot) {
            int best = 0; float bv = -INFINITY;
            for (int o = 0; o < 4; ++o)
                if (!used[o] && logp[o] > bv) { bv = logp[o]; best = o; }
            used[best] = true;
            scores[n * 4 + slot] = bv;
            op0[n * 4 + slot] = best;
            p0[n * 4 + slot] = probs[best];
        }
    }
}

// ---------------------------------------------------------------------------
// K11/K13: beam level >=1: 16 cand = scores[b]+logp[b][o]; stable top-4
// one wave per sample
// ---------------------------------------------------------------------------
__global__ void beam_level(const float* __restrict__ h, const float* __restrict__ Who,
                           const float* __restrict__ bho, float* __restrict__ scores,
                           int* __restrict__ opL, float* __restrict__ pL,
                           int* __restrict__ srcL) {
    __shared__ float logits[16], cand[16], pr[16];
    const int n = blockIdx.x, l = threadIdx.x;
    const int b = l >> 4, o = (l >> 2) & 3, qt = l & 3;
    const float* hr = h + ((size_t)n * 4 + b) * 128;
    float s = 0.f;
    for (int k = qt * 32; k < qt * 32 + 32; ++k) s += hr[k] * Who[k * 4 + o];
    s += __shfl_xor(s, 1);
    s += __shfl_xor(s, 2);
    if (qt == 0) logits[b * 4 + o] = s + bho[o];
    __syncthreads();
    if (l < 4) {
        float lg[4];
#pragma unroll
        for (int o2 = 0; o2 < 4; ++o2) lg[o2] = logits[l * 4 + o2];
        float m = fmaxf(fmaxf(lg[0], lg[1]), fmaxf(lg[2], lg[3]));
        float e[4], sum = 0.f;
#pragma unroll
        for (int o2 = 0; o2 < 4; ++o2) { e[o2] = expf(lg[o2] - m); sum += e[o2]; }
        float lse = logf(sum);
        float sb = scores[n * 4 + l];
#pragma unroll
        for (int o2 = 0; o2 < 4; ++o2) {
            pr[l * 4 + o2] = e[o2] / sum;
            cand[l * 4 + o2] = sb + (lg[o2] - m - lse);
        }
    }
    __syncthreads();
    if (l == 0) {
        bool used[16];
#pragma unroll
        for (int f = 0; f < 16; ++f) used[f] = false;
        float ns[4], np[4]; int nop[4], nsrc[4];
        for (int slot = 0; slot < 4; ++slot) {
            int best = 0; float bv = -INFINITY;
            for (int f = 0; f < 16; ++f)
                if (!used[f] && cand[f] > bv) { bv = cand[f]; best = f; }
            used[best] = true;
            ns[slot] = bv; nsrc[slot] = best >> 2; nop[slot] = best & 3;
            np[slot] = pr[best];
        }
        for (int slot = 0; slot < 4; ++slot) {
            scores[n * 4 + slot] = ns[slot];
            opL[n * 4 + slot] = nop[slot];
            pL[n * 4 + slot] = np[slot];
            srcL[n * 4 + slot] = nsrc[slot];
        }
    }
}

// ---------------------------------------------------------------------------
// K10/K12: h = tanh(src_row @ W_hh + E_op[op] + b_h). 2 rows x 128 cols/block.
// mode 0: src row = h0[r>>2];  mode 1: src row = in[(r&~3)+srcL[r]]
// ---------------------------------------------------------------------------
__global__ __launch_bounds__(256) void h_update(
    const float* __restrict__ in, int mode, const int* __restrict__ srcL,
    const int* __restrict__ opL, const float* __restrict__ Whh,
    const float* __restrict__ Eop, const float* __restrict__ bh,
    float* __restrict__ out) {
    __shared__ float A[256];
    const int r0 = blockIdx.x * 2, t = threadIdx.x;
    const int row = t >> 7, j = t & 127;
    const int r = r0 + row;
    const float* src;
    if (mode == 0) src = in + (size_t)(r >> 2) * 128;
    else           src = in + (size_t)((r & ~3) + srcL[r]) * 128;
    A[t] = src[j];
    __syncthreads();
    float acc = 0.f;
#pragma unroll 8
    for (int k = 0; k < 128; ++k) acc += A[row * 128 + k] * Whh[k * 128 + j];
    out[(size_t)r * 128 + j] = tanhf(acc + Eop[opL[r] * 128 + j] + bh[j]);
}

// ---------------------------------------------------------------------------
// K14-16: dispatch: per row apply only the SELECTED expert (op<3) or identity.
// out = relu((hid @ exp_w[op] + exp_b[op]) * p)  |  relu(hid * p)
// ---------------------------------------------------------------------------
__global__ __launch_bounds__(256) void dispatch_kernel(
    const float* __restrict__ in, int mode, const int* __restrict__ opL,
    const float* __restrict__ pL, const float* __restrict__ expw,
    const float* __restrict__ expb, float* __restrict__ out) {
    __shared__ float A[256];
    const int r0 = blockIdx.x * 2, t = threadIdx.x;
    const int row = t >> 7, j = t & 127;
    const int r = r0 + row;
    const float* src = (mode == 0) ? in + (size_t)(r >> 2) * 128
                                   : in + (size_t)r * 128;
    A[t] = src[j];
    __syncthreads();
    const int op = opL[r];
    const float p = pL[r];
    float res;
    if (op < 3) {
        const float* Bw = expw + (size_t)op * 16384;
        float acc = 0.f;
#pragma unroll 8
        for (int k = 0; k < 128; ++k) acc += A[row * 128 + k] * Bw[k * 128 + j];
        res = (acc + expb[op * 128 + j]) * p;
    } else {
        res = A[row * 128 + j] * p;
    }
    out[(size_t)r * 128 + j] = fmaxf(res, 0.f);
}

// ---------------------------------------------------------------------------
// K17: final head: out = hid @ out_w + out_b  (8192 x 10)
// ---------------------------------------------------------------------------
__global__ void final_kernel(const float* __restrict__ hid, const float* __restrict__ ow,
                             const float* __restrict__ ob, float* __restrict__ out) {
    const int idx = blockIdx.x * 256 + threadIdx.x;
    if (idx >= 81920) return;
    const int r = idx / 10, o = idx % 10;
    const float* hr = hid + (size_t)r * 128;
    float acc = ob[o];
#pragma unroll 8
    for (int k = 0; k < 128; ++k) acc += hr[k] * ow[k * 10 + o];
    out[idx] = acc;
}

// ===========================================================================
extern "C" void kernel_launch(void* const* d_in, const int* in_sizes, int n_in,
                              void* d_out, int out_size, void* d_ws, size_t ws_size,
                              hipStream_t stream) {
    const float* x    = (const float*)d_in[0];
    const float* cw1  = (const float*)d_in[1];
    const float* g1   = (const float*)d_in[3];
    const float* be1  = (const float*)d_in[4];
    const float* cw2  = (const float*)d_in[5];
    const float* g2   = (const float*)d_in[7];
    const float* be2  = (const float*)d_in[8];
    const float* cw3  = (const float*)d_in[9];
    const float* g3   = (const float*)d_in[11];
    const float* be3  = (const float*)d_in[12];
    const float* Whh  = (const float*)d_in[13];
    const float* bh   = (const float*)d_in[14];
    const float* Eop  = (const float*)d_in[15];
    const float* Who  = (const float*)d_in[16];
    const float* bho  = (const float*)d_in[17];
    const float* expw = (const float*)d_in[18];
    const float* expb = (const float*)d_in[19];
    const float* outw = (const float*)d_in[20];
    const float* outb = (const float*)d_in[21];
    float* ws  = (float*)d_ws;
    float* out = (float*)d_out;

    prep_w<<<36, 256, 0, stream>>>(cw1, cw2, cw3, ws + O_W1T, ws + O_W2T, ws + O_W3T);

    // ---- backbone ----
    conv1_stats_kernel<<<2048, 256, 0, stream>>>(x, ws + O_W1T, ws + O_PART);
    finalize_stats<<<1, 256, 0, stream>>>(ws + O_PART, 2048, 1.f / 1843200.f,
                                          g1, be1, ws + O_SC);
    conv1_apply_kernel<<<2048, 256, 0, stream>>>(x, ws + O_W1T, ws + O_SC, ws + O_S1P);
    conv2_kernel<<<2048, 192, 0, stream>>>(ws + O_S1P, ws + O_W2T, ws + O_S2C);
    stats_partial<<<1024, 256, 0, stream>>>(ws + O_S2C, 2048 * 169 * 32, ws + O_PART);
    finalize_stats<<<1, 256, 0, stream>>>(ws + O_PART, 1024, 1.f / 346112.f,
                                          g2, be2, ws + O_SC + 64);
    bn_pool2<<<2048, 256, 0, stream>>>(ws + O_S2C, ws + O_SC + 64, ws + O_S2P);
    conv3_kernel<<<256, 128, 0, stream>>>(ws + O_S2P, ws + O_W3T, ws + O_S3C);
    stats_partial<<<256, 256, 0, stream>>>(ws + O_S3C, 2048 * 16 * 32, ws + O_PART);
    finalize_stats<<<1, 256, 0, stream>>>(ws + O_PART, 256, 1.f / 32768.f,
                                          g3, be3, ws + O_SC + 128);
    bn_pool3_h0<<<1024, 256, 0, stream>>>(ws + O_S3C, ws + O_SC + 128, ws + O_H0);

    // ---- beam search ----
    beam0_kernel<<<2048, 64, 0, stream>>>(ws + O_H0, Who, bho, ws + O_SCORES,
                                          (int*)(ws + O_OP0), ws + O_P0);
    h_update<<<4096, 256, 0, stream>>>(ws + O_H0, 0, (int*)(ws + O_SRC2),
                                       (int*)(ws + O_OP0), Whh, Eop, bh, ws + O_H);
    beam_level<<<2048, 64, 0, stream>>>(ws + O_H, Who, bho, ws + O_SCORES,
                                        (int*)(ws + O_OP1), ws + O_P1,
                                        (int*)(ws + O_SRC1));
    h_update<<<4096, 256, 0, stream>>>(ws + O_H, 1, (int*)(ws + O_SRC1),
                                       (int*)(ws + O_OP1), Whh, Eop, bh, ws + O_H2);
    beam_level<<<2048, 64, 0, stream>>>(ws + O_H2, Who, bho, ws + O_SCORES,
                                        (int*)(ws + O_OP2), ws + O_P2,
                                        (int*)(ws + O_SRC2));

    // ---- expert dispatch (3 rounds) + head ----
    dispatch_kernel<<<4096, 256, 0, stream>>>(ws + O_H0, 0, (int*)(ws + O_OP0),
                                              ws + O_P0, expw, expb, ws + O_HIDA);
    dispatch_kernel<<<4096, 256, 0, stream>>>(ws + O_HIDA, 1, (int*)(ws + O_OP1),
                                              ws + O_P1, expw, expb, ws + O_HIDB);
    dispatch_kernel<<<4096, 256, 0, stream>>>(ws + O_HIDB, 1, (int*)(ws + O_OP2),
                                              ws + O_P2, expw, expb, ws + O_HIDA);
    final_kernel<<<320, 256, 0, stream>>>(ws + O_HIDA, outw, outb, out);
}